// Round 7
// baseline (142.677 us; speedup 1.0000x reference)
//
#include <hip/hip_runtime.h>
#include <hip/hip_fp16.h>

// PQ sim: sim = decode(x) @ decode(tgt)^T via f16 GEMM (K=512).
// R7: BM=BN=128, BK=32, 4 waves (2x2, wave 64x64), ring-of-3 LDS (48 KB)
// -> 3 blocks/CU so epilogue C-write bursts overlap other blocks' compute.
// Counted vmcnt(4) ring (T4), read-side XOR swizzle (T2), setprio (T5),
// XCD-pinned supertile mapping (R6).

#define D_FULL 512
#define M_SUB 64
#define KSUB 256
#define DSUB 8
#define KP 512

typedef _Float16 f16x8 __attribute__((ext_vector_type(8)));
typedef float f32x4 __attribute__((ext_vector_type(4)));

static __device__ __forceinline__ unsigned int pack2h(float f0, float f1) {
  _Float16 h0 = (_Float16)f0, h1 = (_Float16)f1;
  unsigned short u0, u1;
  __builtin_memcpy(&u0, &h0, 2);
  __builtin_memcpy(&u1, &h1, 2);
  return (unsigned int)u0 | ((unsigned int)u1 << 16);
}

// ---------------- encode + decode queries into A' (f16) ----------------
__global__ void encode_kernel(const float* __restrict__ x,
                              const float* __restrict__ cen,
                              unsigned short* __restrict__ Ap) {
  __shared__ float cs[KSUB][DSUB];
  __shared__ float n2[KSUB];
  const int t = threadIdx.x;
  const int s = blockIdx.x;
  const int i = blockIdx.y * 256 + t;

  const float* cp = cen + ((size_t)s * KSUB + t) * DSUB;
  float4 c0 = *(const float4*)cp;
  float4 c1 = *(const float4*)(cp + 4);
  *(float4*)&cs[t][0] = c0;
  *(float4*)&cs[t][4] = c1;
  n2[t] = c0.x * c0.x + c0.y * c0.y + c0.z * c0.z + c0.w * c0.w +
          c1.x * c1.x + c1.y * c1.y + c1.z * c1.z + c1.w * c1.w;
  __syncthreads();

  float xq[8];
  const float* xp = x + (size_t)i * D_FULL + s * DSUB;
  *(float4*)&xq[0] = *(const float4*)xp;
  *(float4*)&xq[4] = *(const float4*)(xp + 4);

  float best = 1e30f;
  int bk = 0;
  for (int k = 0; k < KSUB; ++k) {
    float dot = 0.f;
#pragma unroll
    for (int d = 0; d < 8; ++d) dot += cs[k][d] * xq[d];
    float dis = n2[k] - 2.0f * dot;
    if (dis < best) { best = dis; bk = k; }  // strict < = numpy argmin tie rule
  }

  uint4 hv;
  hv.x = pack2h(cs[bk][0], cs[bk][1]);
  hv.y = pack2h(cs[bk][2], cs[bk][3]);
  hv.z = pack2h(cs[bk][4], cs[bk][5]);
  hv.w = pack2h(cs[bk][6], cs[bk][7]);
  *(uint4*)(Ap + (size_t)i * KP + s * DSUB) = hv;
}

// ---------------- decode targets into B' (f16) ----------------
__global__ void decode_tgt(const int* __restrict__ tgt,
                           const float* __restrict__ cen,
                           unsigned short* __restrict__ Bp) {
  int g = blockIdx.x * 256 + threadIdx.x;
  int j = g >> 6, s = g & 63;
  int k = tgt[g];
  const float* c = cen + ((size_t)s * KSUB + k) * DSUB;
  float4 v0 = *(const float4*)c;
  float4 v1 = *(const float4*)(c + 4);
  uint4 hv;
  hv.x = pack2h(v0.x, v0.y);
  hv.y = pack2h(v0.z, v0.w);
  hv.z = pack2h(v1.x, v1.y);
  hv.w = pack2h(v1.z, v1.w);
  *(uint4*)(Bp + (size_t)j * KP + s * DSUB) = hv;
}

// ---------------- GEMM: C[n,m] = A'[n,KP] * B'[m,KP]^T ----------------
// Slot (16 KB): A 128x32 f16 (8 KB) + B 128x32 f16 (8 KB). Row = 64 B =
// 4 chunks of 16 B. Physical chunk p at row r holds logical chunk p^(r&3)
// (involution; stage uses linear LDS dest + inverse-swizzled global src,
// rule #21; read XORs back -> 2 lanes/bank, conflict-free).
#define STAGE(T, SLOT)                                                          \
  do {                                                                          \
    const int k0_ = (T) * 32;                                                   \
    unsigned short* as_ = lds + (SLOT) * 8192;                                  \
    unsigned short* bs_ = as_ + 4096;                                           \
    _Pragma("unroll") for (int L = 0; L < 2; ++L) {                             \
      int R = L * 64 + (tid >> 2);                                              \
      int c = (tid & 3) ^ (R & 3);                                              \
      __builtin_amdgcn_global_load_lds(                                         \
          (const __attribute__((address_space(1))) void*)(Ab + (size_t)R * KP + \
                                                          k0_ + c * 8),         \
          (__attribute__((address_space(3))) void*)(as_ + L * 2048 + tid * 8),  \
          16, 0, 0);                                                            \
    }                                                                           \
    _Pragma("unroll") for (int L = 0; L < 2; ++L) {                             \
      int R = L * 64 + (tid >> 2);                                              \
      int c = (tid & 3) ^ (R & 3);                                              \
      __builtin_amdgcn_global_load_lds(                                         \
          (const __attribute__((address_space(1))) void*)(Bb + (size_t)R * KP + \
                                                          k0_ + c * 8),         \
          (__attribute__((address_space(3))) void*)(bs_ + L * 2048 + tid * 8),  \
          16, 0, 0);                                                            \
    }                                                                           \
  } while (0)

// Consume one BK=32 tile from SLOT: 8 ds_read_b128 + 16 MFMA per wave.
#define COMPUTE(SLOT)                                                           \
  do {                                                                          \
    const unsigned short* as_ = lds + (SLOT) * 8192;                            \
    const unsigned short* bs_ = as_ + 4096;                                     \
    f16x8 a_[4], b_[4];                                                         \
    _Pragma("unroll") for (int i2 = 0; i2 < 4; ++i2) {                          \
      int row = wm * 64 + i2 * 16 + l16;                                        \
      a_[i2] = *(const f16x8*)&as_[row * 32 + ((kq ^ (row & 3)) * 8)];          \
    }                                                                           \
    _Pragma("unroll") for (int j2 = 0; j2 < 4; ++j2) {                          \
      int row = wn * 64 + j2 * 16 + l16;                                        \
      b_[j2] = *(const f16x8*)&bs_[row * 32 + ((kq ^ (row & 3)) * 8)];          \
    }                                                                           \
    __builtin_amdgcn_s_setprio(1);                                              \
    _Pragma("unroll") for (int i2 = 0; i2 < 4; ++i2)                            \
        _Pragma("unroll") for (int j2 = 0; j2 < 4; ++j2) acc[i2][j2] =          \
        __builtin_amdgcn_mfma_f32_16x16x32_f16(a_[i2], b_[j2], acc[i2][j2], 0,  \
                                               0, 0);                           \
    __builtin_amdgcn_s_setprio(0);                                              \
  } while (0)

#define VMW(N) asm volatile("s_waitcnt vmcnt(" #N ")" ::: "memory")
#define BAR() __builtin_amdgcn_s_barrier()

__global__ __launch_bounds__(256, 3) void gemm_nt(
    const unsigned short* __restrict__ A, const unsigned short* __restrict__ B,
    float* __restrict__ C, int Nt) {
  __shared__ unsigned short lds[3 * 8192];  // 48 KB -> 3 blocks/CU
  const int tid = threadIdx.x;
  const int w = tid >> 6, l = tid & 63;
  const int wm = w >> 1, wn = w & 1;
  const int l16 = l & 15, kq = l >> 4;

  // XCD-pinned mapping: XCD x owns bn in [x*16, x*16+16) (2 MB B, L2-resident
  // all kernel). Within XCD: 8bm x 16bn supertiles walked bm-fastest, so the
  // ~96 concurrent blocks/XCD share ~1 MB A + ~2 MB B in L2.
  const int bid = blockIdx.x;
  const int xcd = bid & 7;
  const int idx = bid >> 3;                   // 0..511
  const int bm = (idx >> 7) * 8 + (idx & 7);  // 0..31
  const int bn = xcd * 16 + ((idx >> 3) & 15);  // 0..127

  const unsigned short* Ab = A + (size_t)bm * 128 * KP;
  const unsigned short* Bb = B + (size_t)bn * 128 * KP;

  f32x4 acc[4][4] = {};

  // Ring-of-3, depth-2 prefetch, 4 loads/wave/tile. Prologue: drain tile0.
  STAGE(0, 0);
  STAGE(1, 1);
  VMW(4);
  BAR();

  // Iter t: stage t+2 (into slot of t-1, freed at last barrier), compute t,
  // drain t+1's 4 loads (leave t+2's 4 in flight).
  STAGE(2, 2);  COMPUTE(0); VMW(4); BAR();   // t=0
  STAGE(3, 0);  COMPUTE(1); VMW(4); BAR();   // t=1
  STAGE(4, 1);  COMPUTE(2); VMW(4); BAR();   // t=2
  STAGE(5, 2);  COMPUTE(0); VMW(4); BAR();   // t=3
  STAGE(6, 0);  COMPUTE(1); VMW(4); BAR();   // t=4
  STAGE(7, 1);  COMPUTE(2); VMW(4); BAR();   // t=5
  STAGE(8, 2);  COMPUTE(0); VMW(4); BAR();   // t=6
  STAGE(9, 0);  COMPUTE(1); VMW(4); BAR();   // t=7
  STAGE(10, 1); COMPUTE(2); VMW(4); BAR();   // t=8
  STAGE(11, 2); COMPUTE(0); VMW(4); BAR();   // t=9
  STAGE(12, 0); COMPUTE(1); VMW(4); BAR();   // t=10
  STAGE(13, 1); COMPUTE(2); VMW(4); BAR();   // t=11
  STAGE(14, 2); COMPUTE(0); VMW(4); BAR();   // t=12
  STAGE(15, 0); COMPUTE(1); VMW(4); BAR();   // t=13
  COMPUTE(2); VMW(0); BAR();                 // t=14 (drain tile 15)
  COMPUTE(0);                                // t=15

  // Epilogue: C/D layout col=lane&15, row=(lane>>4)*4+reg (m89/m91).
  const int rb = bm * 128 + wm * 64 + (l >> 4) * 4;
  const int cb = bn * 128 + wn * 64 + l16;
#pragma unroll
  for (int i2 = 0; i2 < 4; ++i2)
#pragma unroll
    for (int j2 = 0; j2 < 4; ++j2)
#pragma unroll
      for (int r = 0; r < 4; ++r)
        C[(size_t)(rb + i2 * 16 + r) * Nt + cb + j2 * 16] = acc[i2][j2][r];
}

extern "C" void kernel_launch(void* const* d_in, const int* in_sizes, int n_in,
                              void* d_out, int out_size, void* d_ws, size_t ws_size,
                              hipStream_t stream) {
  const float* x = (const float*)d_in[0];    // [n, 512]
  const float* cen = (const float*)d_in[1];  // [64, 256, 8]
  const int* tgt = (const int*)d_in[2];      // [m, 64]
  float* out = (float*)d_out;                // [n, m]
  const int n = in_sizes[0] / D_FULL;        // 4096
  const int m = in_sizes[2] / M_SUB;         // 16384

  unsigned short* Ap = (unsigned short*)d_ws;  // [n, 512] f16
  unsigned short* Bp = Ap + (size_t)n * KP;    // [m, 512] f16

  encode_kernel<<<dim3(M_SUB, n / 256), 256, 0, stream>>>(x, cen, Ap);
  decode_tgt<<<dim3((m * M_SUB) / 256), 256, 0, stream>>>(tgt, cen, Bp);
  gemm_nt<<<dim3((n / 128) * (m / 128)), 256, 0, stream>>>(Ap, Bp, out, m);
}